// Round 1
// baseline (1305.562 us; speedup 1.0000x reference)
//
#include <hip/hip_runtime.h>
#include <math.h>

// ---------------------------------------------------------------------------
// fp32 tiled GEMM: C[M x N] = A[M x K] * op(B) (+ bias)
//   TRANS_B = false: B is (K x N) row-major (NN)
//   TRANS_B = true : B is (N x K) row-major (NT, C = A * B^T)
// 64x64 tile, BK=16, 256 threads, 4x4 accumulators per thread.
// M may be ragged (guards); N and K assumed multiples of 64 / 16 (true here).
// ---------------------------------------------------------------------------
#define TILE_M 64
#define TILE_N 64
#define TILE_K 16

template <bool TRANS_B, bool HAS_BIAS>
__global__ __launch_bounds__(256) void gemm_kernel(
    const float* __restrict__ A, const float* __restrict__ B,
    const float* __restrict__ bias, float* __restrict__ C,
    int M, int N, int K)
{
    __shared__ float As[TILE_K][TILE_M + 1];
    __shared__ float Bs[TILE_K][TILE_N + 1];

    const int tid = threadIdx.x;
    const int tx = tid & 15;      // 0..15  -> 4 output cols each
    const int ty = tid >> 4;      // 0..15  -> 4 output rows each
    const int bm = blockIdx.y * TILE_M;
    const int bn = blockIdx.x * TILE_N;

    float acc[4][4];
#pragma unroll
    for (int i = 0; i < 4; ++i)
#pragma unroll
        for (int j = 0; j < 4; ++j) acc[i][j] = 0.f;

    for (int k0 = 0; k0 < K; k0 += TILE_K) {
        // A tile: 64 rows x 16 k  (consecutive tids read consecutive k)
#pragma unroll
        for (int i = 0; i < 4; ++i) {
            int idx = tid + i * 256;      // 0..1023
            int kk = idx & 15;
            int mm = idx >> 4;
            int gm = bm + mm;
            As[kk][mm] = (gm < M) ? A[(size_t)gm * K + (k0 + kk)] : 0.f;
        }
        if (TRANS_B) {
#pragma unroll
            for (int i = 0; i < 4; ++i) {
                int idx = tid + i * 256;
                int kk = idx & 15;
                int nn = idx >> 4;
                Bs[kk][nn] = B[(size_t)(bn + nn) * K + (k0 + kk)];
            }
        } else {
#pragma unroll
            for (int i = 0; i < 4; ++i) {
                int idx = tid + i * 256;
                int nn = idx & 63;        // consecutive tids -> consecutive n
                int kk = idx >> 6;
                Bs[kk][nn] = B[(size_t)(k0 + kk) * N + (bn + nn)];
            }
        }
        __syncthreads();

#pragma unroll
        for (int kk = 0; kk < TILE_K; ++kk) {
            float a[4], b[4];
#pragma unroll
            for (int i = 0; i < 4; ++i) a[i] = As[kk][ty * 4 + i];
#pragma unroll
            for (int j = 0; j < 4; ++j) b[j] = Bs[kk][tx * 4 + j];
#pragma unroll
            for (int i = 0; i < 4; ++i)
#pragma unroll
                for (int j = 0; j < 4; ++j)
                    acc[i][j] = fmaf(a[i], b[j], acc[i][j]);
        }
        __syncthreads();
    }

#pragma unroll
    for (int i = 0; i < 4; ++i) {
        int gm = bm + ty * 4 + i;
        if (gm >= M) continue;
#pragma unroll
        for (int j = 0; j < 4; ++j) {
            int gn = bn + tx * 4 + j;
            float v = acc[i][j];
            if (HAS_BIAS) v += bias[gn];
            C[(size_t)gm * N + gn] = v;
        }
    }
}

// ---------------------------------------------------------------------------
// Row softmax, in place. One block (256 threads) per row, L <= 2048.
// ---------------------------------------------------------------------------
__global__ __launch_bounds__(256) void softmax_kernel(float* __restrict__ S, int L)
{
    __shared__ float row[2048];
    __shared__ float red[8];
    const int tid = threadIdx.x;
    float* p = S + (size_t)blockIdx.x * L;

    float mx = -1e30f;
    for (int i = tid; i < L; i += 256) {
        float v = p[i];
        row[i] = v;
        mx = fmaxf(mx, v);
    }
#pragma unroll
    for (int o = 32; o; o >>= 1) mx = fmaxf(mx, __shfl_down(mx, o));
    if ((tid & 63) == 0) red[tid >> 6] = mx;
    __syncthreads();
    if (tid == 0) red[4] = fmaxf(fmaxf(red[0], red[1]), fmaxf(red[2], red[3]));
    __syncthreads();
    mx = red[4];

    float sum = 0.f;
    for (int i = tid; i < L; i += 256) {
        float e = expf(row[i] - mx);
        row[i] = e;
        sum += e;
    }
#pragma unroll
    for (int o = 32; o; o >>= 1) sum += __shfl_down(sum, o);
    if ((tid & 63) == 0) red[tid >> 6] = sum;
    __syncthreads();
    if (tid == 0) red[5] = red[0] + red[1] + red[2] + red[3];
    __syncthreads();
    float inv = 1.f / red[5];
    for (int i = tid; i < L; i += 256) p[i] = row[i] * inv;
}

// ---------------------------------------------------------------------------
// Row-wise L2 normalize, in place. One block (256 threads) per row of D elems.
// ---------------------------------------------------------------------------
__global__ __launch_bounds__(256) void l2norm_kernel(float* __restrict__ V, int D)
{
    __shared__ float red[8];
    const int tid = threadIdx.x;
    float* p = V + (size_t)blockIdx.x * D;

    float s = 0.f;
    for (int i = tid; i < D; i += 256) {
        float v = p[i];
        s = fmaf(v, v, s);
    }
#pragma unroll
    for (int o = 32; o; o >>= 1) s += __shfl_down(s, o);
    if ((tid & 63) == 0) red[tid >> 6] = s;
    __syncthreads();
    if (tid == 0) red[4] = red[0] + red[1] + red[2] + red[3];
    __syncthreads();
    float scale = 1.f / sqrtf(red[4]);
    for (int i = tid; i < D; i += 256) p[i] *= scale;
}

// ---------------------------------------------------------------------------
// Orchestration. Only batch 0 influences the output (attention is per-batch,
// and the reference returns final[0, -1, :]); block 3 needs only the last
// query row. Buffers aliased: bufK holds k1/k2/k3, bufQ holds q1/q2/q3,
// H holds out1/hidden, V holds v2/v3, Sc holds scores (+ the 1-row scores).
// Total ws: 7,340,032 floats = 28 MiB.
// ---------------------------------------------------------------------------
extern "C" void kernel_launch(void* const* d_in, const int* in_sizes, int n_in,
                              void* d_out, int out_size, void* d_ws, size_t ws_size,
                              hipStream_t stream)
{
    const float* x   = (const float*)d_in[0];   // (8,2048,512); batch 0 = first 2048*512
    const float* Wk1 = (const float*)d_in[1];
    const float* bk1 = (const float*)d_in[2];
    const float* Wq1 = (const float*)d_in[3];
    const float* bq1 = (const float*)d_in[4];
    const float* Wk2 = (const float*)d_in[5];
    const float* bk2 = (const float*)d_in[6];
    const float* Wq2 = (const float*)d_in[7];
    const float* bq2 = (const float*)d_in[8];
    const float* Wv2 = (const float*)d_in[9];
    const float* bv2 = (const float*)d_in[10];
    float* out = (float*)d_out;

    const int S = 2048, D = 512, Kd = 256;

    float* ws   = (float*)d_ws;
    float* bufK = ws;                         // S*Kd
    float* bufQ = bufK + (size_t)S * Kd;      // S*Kd
    float* Sc   = bufQ + (size_t)S * Kd;      // S*S
    float* H    = Sc + (size_t)S * S;         // S*D (out1, then hidden)
    float* V    = H + (size_t)S * D;          // S*D (v2, then v3)

    dim3 blk(256);
    auto g = [](int n, int m) { return dim3((n + 63) / 64, (m + 63) / 64); };

    // ---- block 1: k1/q1 proj, attn with v = x ----
    gemm_kernel<false, true><<<g(Kd, S), blk, 0, stream>>>(x, Wk1, bk1, bufK, S, Kd, D);
    gemm_kernel<false, true><<<g(Kd, S), blk, 0, stream>>>(x, Wq1, bq1, bufQ, S, Kd, D);
    gemm_kernel<true, false><<<g(S, S), blk, 0, stream>>>(bufQ, bufK, nullptr, Sc, S, S, Kd);
    softmax_kernel<<<dim3(S), blk, 0, stream>>>(Sc, S);
    gemm_kernel<false, false><<<g(D, S), blk, 0, stream>>>(Sc, x, nullptr, H, S, D, S);

    // ---- block 2: hidden = block2(out1) ----
    gemm_kernel<false, true><<<g(Kd, S), blk, 0, stream>>>(H, Wk2, bk2, bufK, S, Kd, D);
    gemm_kernel<false, true><<<g(Kd, S), blk, 0, stream>>>(H, Wq2, bq2, bufQ, S, Kd, D);
    gemm_kernel<false, true><<<g(D, S), blk, 0, stream>>>(H, Wv2, bv2, V, S, D, D);
    l2norm_kernel<<<dim3(S), blk, 0, stream>>>(V, D);
    gemm_kernel<true, false><<<g(S, S), blk, 0, stream>>>(bufQ, bufK, nullptr, Sc, S, S, Kd);
    softmax_kernel<<<dim3(S), blk, 0, stream>>>(Sc, S);
    gemm_kernel<false, false><<<g(D, S), blk, 0, stream>>>(Sc, V, nullptr, H, S, D, S);

    // ---- block 3: final = block2(hidden), only last query row needed ----
    gemm_kernel<false, true><<<g(Kd, S), blk, 0, stream>>>(H, Wk2, bk2, bufK, S, Kd, D);
    gemm_kernel<false, true><<<g(D, S), blk, 0, stream>>>(H, Wv2, bv2, V, S, D, D);
    l2norm_kernel<<<dim3(S), blk, 0, stream>>>(V, D);
    // q3 from the last row of hidden only
    gemm_kernel<false, true><<<g(Kd, 1), blk, 0, stream>>>(H + (size_t)(S - 1) * D, Wq2, bq2,
                                                           bufQ, 1, Kd, D);
    gemm_kernel<true, false><<<g(S, 1), blk, 0, stream>>>(bufQ, bufK, nullptr, Sc, 1, S, Kd);
    softmax_kernel<<<dim3(1), blk, 0, stream>>>(Sc, S);
    gemm_kernel<false, false><<<g(D, 1), blk, 0, stream>>>(Sc, V, nullptr, out, 1, D, S);
}

// Round 2
// 999.858 us; speedup vs baseline: 1.3057x; 1.3057x over previous
//
#include <hip/hip_runtime.h>
#include <math.h>

typedef __attribute__((ext_vector_type(8))) short short8;
typedef __attribute__((ext_vector_type(4))) float f32x4;

#define BM 128
#define BN 128
#define BK 32

// ---------------------------------------------------------------------------
// fp32 <-> bf16 helpers (round-to-nearest-even-ish via +0x7FFF+lsb trick)
// ---------------------------------------------------------------------------
__device__ inline unsigned short f2bf_rn(float f) {
    unsigned u = __builtin_bit_cast(unsigned, f);
    u += 0x7FFF + ((u >> 16) & 1);
    return (unsigned short)(u >> 16);
}
__device__ inline float bf2f(unsigned short h) {
    unsigned u = ((unsigned)h) << 16;
    return __builtin_bit_cast(float, u);
}

// ---------------------------------------------------------------------------
// Stage a 128 x 32 fp32 tile into hi/lo bf16 LDS tiles with XOR swizzle.
// Swizzle: 16B slot index s (k/8) stored at s ^ ((row>>1)&3)  -> ~2-way banks.
// ---------------------------------------------------------------------------
__device__ inline void stage_tile(const float* __restrict__ G, int ldg,
                                  int row0, int k0,
                                  unsigned short (*H)[BK], unsigned short (*L)[BK])
{
#pragma unroll
    for (int i = 0; i < 4; ++i) {
        int idx = (int)threadIdx.x + i * 256;   // 0..1023 float4s
        int row = idx >> 3;                      // 0..127
        int kq  = idx & 7;                       // float4 slot within row
        const float4 v = *reinterpret_cast<const float4*>(
            &G[(size_t)(row0 + row) * ldg + k0 + kq * 4]);
        unsigned short h0 = f2bf_rn(v.x), h1 = f2bf_rn(v.y),
                       h2 = f2bf_rn(v.z), h3 = f2bf_rn(v.w);
        unsigned short l0 = f2bf_rn(v.x - bf2f(h0)), l1 = f2bf_rn(v.y - bf2f(h1)),
                       l2 = f2bf_rn(v.z - bf2f(h2)), l3 = f2bf_rn(v.w - bf2f(h3));
        int col = (((kq >> 1) ^ ((row >> 1) & 3)) << 3) + ((kq & 1) << 2);
        uint2 ph = make_uint2((unsigned)h0 | ((unsigned)h1 << 16),
                              (unsigned)h2 | ((unsigned)h3 << 16));
        uint2 pl = make_uint2((unsigned)l0 | ((unsigned)l1 << 16),
                              (unsigned)l2 | ((unsigned)l3 << 16));
        *reinterpret_cast<uint2*>(&H[row][col]) = ph;
        *reinterpret_cast<uint2*>(&L[row][col]) = pl;
    }
}

// ---------------------------------------------------------------------------
// Split-precision bf16 MFMA GEMM, NT:  C[M x N] = A[M x K] * Bt[N x K]^T (+bias)
// A, Bt fp32 row-major (k-contiguous both sides). M,N % 128 == 0, K % 32 == 0.
// 128x128 tile, 4 waves (2x2 of 64x64), 3 MFMA passes (hh + hl + lh).
// ---------------------------------------------------------------------------
template <bool HAS_BIAS>
__global__ __launch_bounds__(256, 2) void gemm_nt_split(
    const float* __restrict__ A, int lda,
    const float* __restrict__ Bt, int ldb,
    const float* __restrict__ bias,
    float* __restrict__ C, int ldc,
    int K)
{
    __shared__ unsigned short AsH[BM][BK], AsL[BM][BK];
    __shared__ unsigned short BsH[BN][BK], BsL[BN][BK];

    const int tid  = threadIdx.x;
    const int lane = tid & 63;
    const int w    = tid >> 6;
    const int wm   = w >> 1, wn = w & 1;
    const int bm   = blockIdx.y * BM, bn = blockIdx.x * BN;
    const int r15  = lane & 15, ksl = lane >> 4;

    f32x4 acc[4][4];
#pragma unroll
    for (int i = 0; i < 4; ++i)
#pragma unroll
        for (int j = 0; j < 4; ++j) acc[i][j] = (f32x4){0.f, 0.f, 0.f, 0.f};

    for (int k0 = 0; k0 < K; k0 += BK) {
        stage_tile(A, lda, bm, k0, AsH, AsL);
        stage_tile(Bt, ldb, bn, k0, BsH, BsL);
        __syncthreads();

        short8 aH[4], aL[4], bH[4], bL[4];
#pragma unroll
        for (int f = 0; f < 4; ++f) {
            int ar = wm * 64 + f * 16 + r15;
            int ac = ((ksl ^ ((ar >> 1) & 3)) << 3);
            aH[f] = *reinterpret_cast<const short8*>(&AsH[ar][ac]);
            aL[f] = *reinterpret_cast<const short8*>(&AsL[ar][ac]);
            int br = wn * 64 + f * 16 + r15;
            int bc = ((ksl ^ ((br >> 1) & 3)) << 3);
            bH[f] = *reinterpret_cast<const short8*>(&BsH[br][bc]);
            bL[f] = *reinterpret_cast<const short8*>(&BsL[br][bc]);
        }

#pragma unroll
        for (int i = 0; i < 4; ++i)
#pragma unroll
            for (int j = 0; j < 4; ++j) {
                acc[i][j] = __builtin_amdgcn_mfma_f32_16x16x32_bf16(aL[i], bH[j], acc[i][j], 0, 0, 0);
                acc[i][j] = __builtin_amdgcn_mfma_f32_16x16x32_bf16(aH[i], bL[j], acc[i][j], 0, 0, 0);
                acc[i][j] = __builtin_amdgcn_mfma_f32_16x16x32_bf16(aH[i], bH[j], acc[i][j], 0, 0, 0);
            }
        __syncthreads();
    }

    // epilogue: C/D layout col = lane&15, row = (lane>>4)*4 + reg
#pragma unroll
    for (int i = 0; i < 4; ++i) {
        int rowb = bm + wm * 64 + i * 16 + (lane >> 4) * 4;
#pragma unroll
        for (int j = 0; j < 4; ++j) {
            int colb = bn + wn * 64 + j * 16 + r15;
            float bv = HAS_BIAS ? bias[colb] : 0.f;
#pragma unroll
            for (int r = 0; r < 4; ++r)
                C[(size_t)(rowb + r) * ldc + colb] = acc[i][j][r] + bv;
        }
    }
}

// ---------------------------------------------------------------------------
// 32x32 tiled transpose: out[C x R] = in[R x C]^T. R, C multiples of 32.
// grid (C/32, R/32), 256 threads.
// ---------------------------------------------------------------------------
__global__ __launch_bounds__(256) void transpose_kernel(
    const float* __restrict__ in, float* __restrict__ out, int R, int C)
{
    __shared__ float tile[32][33];
    int bx = blockIdx.x * 32, by = blockIdx.y * 32;
    int tx = threadIdx.x & 31, ty = threadIdx.x >> 5;   // ty 0..7
#pragma unroll
    for (int i = 0; i < 32; i += 8)
        tile[ty + i][tx] = in[(size_t)(by + ty + i) * C + bx + tx];
    __syncthreads();
#pragma unroll
    for (int i = 0; i < 32; i += 8)
        out[(size_t)(bx + ty + i) * R + by + tx] = tile[tx][ty + i];
}

// ---------------------------------------------------------------------------
// gemv (NT): out[n] = sum_k a[k] * Bt[n][k] (+bias). One wave per n.
// grid N/4, 256 threads. K multiple of 64.
// ---------------------------------------------------------------------------
template <bool HAS_BIAS>
__global__ __launch_bounds__(256) void gemv_nt(
    const float* __restrict__ a, const float* __restrict__ Bt, int ldb,
    const float* __restrict__ bias, float* __restrict__ out, int K)
{
    int w = threadIdx.x >> 6, lane = threadIdx.x & 63;
    int n = blockIdx.x * 4 + w;
    const float* row = Bt + (size_t)n * ldb;
    float s = 0.f;
    for (int k = lane; k < K; k += 64) s = fmaf(a[k], row[k], s);
#pragma unroll
    for (int o = 32; o; o >>= 1) s += __shfl_down(s, o);
    if (lane == 0) out[n] = HAS_BIAS ? s + bias[n] : s;
}

// ---------------------------------------------------------------------------
// Row softmax, in place. One block (256 threads) per row, L <= 2048.
// ---------------------------------------------------------------------------
__global__ __launch_bounds__(256) void softmax_kernel(float* __restrict__ S, int L)
{
    __shared__ float row[2048];
    __shared__ float red[8];
    const int tid = threadIdx.x;
    float* p = S + (size_t)blockIdx.x * L;

    float mx = -1e30f;
    for (int i = tid; i < L; i += 256) {
        float v = p[i];
        row[i] = v;
        mx = fmaxf(mx, v);
    }
#pragma unroll
    for (int o = 32; o; o >>= 1) mx = fmaxf(mx, __shfl_down(mx, o));
    if ((tid & 63) == 0) red[tid >> 6] = mx;
    __syncthreads();
    if (tid == 0) red[4] = fmaxf(fmaxf(red[0], red[1]), fmaxf(red[2], red[3]));
    __syncthreads();
    mx = red[4];

    float sum = 0.f;
    for (int i = tid; i < L; i += 256) {
        float e = expf(row[i] - mx);
        row[i] = e;
        sum += e;
    }
#pragma unroll
    for (int o = 32; o; o >>= 1) sum += __shfl_down(sum, o);
    if ((tid & 63) == 0) red[tid >> 6] = sum;
    __syncthreads();
    if (tid == 0) red[5] = red[0] + red[1] + red[2] + red[3];
    __syncthreads();
    float inv = 1.f / red[5];
    for (int i = tid; i < L; i += 256) p[i] = row[i] * inv;
}

// ---------------------------------------------------------------------------
// Row-wise L2 normalize, in place. One block per row of D elems.
// ---------------------------------------------------------------------------
__global__ __launch_bounds__(256) void l2norm_kernel(float* __restrict__ V, int D)
{
    __shared__ float red[8];
    const int tid = threadIdx.x;
    float* p = V + (size_t)blockIdx.x * D;
    float s = 0.f;
    for (int i = tid; i < D; i += 256) {
        float v = p[i];
        s = fmaf(v, v, s);
    }
#pragma unroll
    for (int o = 32; o; o >>= 1) s += __shfl_down(s, o);
    if ((tid & 63) == 0) red[tid >> 6] = s;
    __syncthreads();
    if (tid == 0) red[4] = red[0] + red[1] + red[2] + red[3];
    __syncthreads();
    float scale = 1.f / sqrtf(red[4]);
    for (int i = tid; i < D; i += 256) p[i] *= scale;
}

// ---------------------------------------------------------------------------
// Orchestration. Batch 0 only (attention is per-batch; output = final[0,-1,:]).
// All GEMMs NT via pre-transposed operands (T buffer holds x^T then V^T).
// ---------------------------------------------------------------------------
extern "C" void kernel_launch(void* const* d_in, const int* in_sizes, int n_in,
                              void* d_out, int out_size, void* d_ws, size_t ws_size,
                              hipStream_t stream)
{
    const float* x   = (const float*)d_in[0];   // batch 0 = first 2048*512
    const float* Wk1 = (const float*)d_in[1];
    const float* bk1 = (const float*)d_in[2];
    const float* Wq1 = (const float*)d_in[3];
    const float* bq1 = (const float*)d_in[4];
    const float* Wk2 = (const float*)d_in[5];
    const float* bk2 = (const float*)d_in[6];
    const float* Wq2 = (const float*)d_in[7];
    const float* bq2 = (const float*)d_in[8];
    const float* Wv2 = (const float*)d_in[9];
    const float* bv2 = (const float*)d_in[10];
    float* out = (float*)d_out;

    const int S = 2048, D = 512, Kd = 256;

    float* ws   = (float*)d_ws;
    float* Sc   = ws;                          // S*S
    float* H    = Sc + (size_t)S * S;          // S*D
    float* V    = H + (size_t)S * D;           // S*D
    float* T    = V + (size_t)S * D;           // D*S (x^T, then V^T)
    float* bufK = T + (size_t)D * S;           // S*Kd
    float* bufQ = bufK + (size_t)S * Kd;       // S*Kd
    float* WTk1 = bufQ + (size_t)S * Kd;       // Kd*D
    float* WTq1 = WTk1 + (size_t)Kd * D;
    float* WTk2 = WTq1 + (size_t)Kd * D;
    float* WTq2 = WTk2 + (size_t)Kd * D;
    float* WTv2 = WTq2 + (size_t)Kd * D;       // D*D

    dim3 blk(256);
    auto gg = [](int N, int M) { return dim3(N / BN, M / BM); };

    // ---- transposes (weights + x) ----
    transpose_kernel<<<dim3(Kd / 32, D / 32), blk, 0, stream>>>(Wk1, WTk1, D, Kd);
    transpose_kernel<<<dim3(Kd / 32, D / 32), blk, 0, stream>>>(Wq1, WTq1, D, Kd);
    transpose_kernel<<<dim3(Kd / 32, D / 32), blk, 0, stream>>>(Wk2, WTk2, D, Kd);
    transpose_kernel<<<dim3(Kd / 32, D / 32), blk, 0, stream>>>(Wq2, WTq2, D, Kd);
    transpose_kernel<<<dim3(D / 32, D / 32), blk, 0, stream>>>(Wv2, WTv2, D, D);
    transpose_kernel<<<dim3(D / 32, S / 32), blk, 0, stream>>>(x, T, S, D);

    // ---- block 1 ----
    gemm_nt_split<true><<<gg(Kd, S), blk, 0, stream>>>(x, D, WTk1, D, bk1, bufK, Kd, D);
    gemm_nt_split<true><<<gg(Kd, S), blk, 0, stream>>>(x, D, WTq1, D, bq1, bufQ, Kd, D);
    gemm_nt_split<false><<<gg(S, S), blk, 0, stream>>>(bufQ, Kd, bufK, Kd, nullptr, Sc, S, Kd);
    softmax_kernel<<<dim3(S), blk, 0, stream>>>(Sc, S);
    gemm_nt_split<false><<<gg(D, S), blk, 0, stream>>>(Sc, S, T, S, nullptr, H, D, S);

    // ---- block 2 ----
    gemm_nt_split<true><<<gg(Kd, S), blk, 0, stream>>>(H, D, WTk2, D, bk2, bufK, Kd, D);
    gemm_nt_split<true><<<gg(Kd, S), blk, 0, stream>>>(H, D, WTq2, D, bq2, bufQ, Kd, D);
    gemm_nt_split<true><<<gg(D, S), blk, 0, stream>>>(H, D, WTv2, D, bv2, V, D, D);
    l2norm_kernel<<<dim3(S), blk, 0, stream>>>(V, D);
    transpose_kernel<<<dim3(D / 32, S / 32), blk, 0, stream>>>(V, T, S, D);
    gemm_nt_split<false><<<gg(S, S), blk, 0, stream>>>(bufQ, Kd, bufK, Kd, nullptr, Sc, S, Kd);
    softmax_kernel<<<dim3(S), blk, 0, stream>>>(Sc, S);
    gemm_nt_split<false><<<gg(D, S), blk, 0, stream>>>(Sc, S, T, S, nullptr, H, D, S);

    // ---- block 3 (only last query row needed) ----
    gemm_nt_split<true><<<gg(Kd, S), blk, 0, stream>>>(H, D, WTk2, D, bk2, bufK, Kd, D);
    gemm_nt_split<true><<<gg(D, S), blk, 0, stream>>>(H, D, WTv2, D, bv2, V, D, D);
    l2norm_kernel<<<dim3(S), blk, 0, stream>>>(V, D);
    transpose_kernel<<<dim3(D / 32, S / 32), blk, 0, stream>>>(V, T, S, D);
    // q3 = H[last] @ Wq2 + bq2  (one row)
    gemv_nt<true><<<dim3(Kd / 4), blk, 0, stream>>>(H + (size_t)(S - 1) * D, WTq2, D, bq2, bufQ, D);
    // scores row = q3 . k3^T
    gemv_nt<false><<<dim3(S / 4), blk, 0, stream>>>(bufQ, bufK, Kd, nullptr, Sc, Kd);
    softmax_kernel<<<dim3(1), blk, 0, stream>>>(Sc, S);
    // out = softmax_row @ V3  (via V3^T in T)
    gemv_nt<false><<<dim3(D / 4), blk, 0, stream>>>(Sc, T, S, nullptr, out, S);
}

// Round 3
// 476.863 us; speedup vs baseline: 2.7378x; 2.0967x over previous
//
#include <hip/hip_runtime.h>
#include <math.h>

typedef __attribute__((ext_vector_type(8))) short short8;
typedef __attribute__((ext_vector_type(4))) float f32x4;

__device__ inline unsigned short f2bf_rn(float f) {
    unsigned u = __builtin_bit_cast(unsigned, f);
    u += 0x7FFF + ((u >> 16) & 1);
    return (unsigned short)(u >> 16);
}
__device__ inline float bf2f(unsigned short h) {
    unsigned u = ((unsigned)h) << 16;
    return __builtin_bit_cast(float, u);
}

// ---------------------------------------------------------------------------
// Pure-bf16 NT GEMM over virtual K' = 3*KSEG (segments: Ah*Bh, Ah*Bl, Al*Bh,
// one fp32 accumulator). 128x128 tile, BK=64, 4 waves (2x2 of 64x64).
// Reg-staged prefetch: tile t+1 global loads issued before tile t's MFMA
// phase; raw s_barrier + lgkmcnt(0) only (no vmcnt(0) drain at the barrier).
// LDS XOR swizzle: 16B slot s stored at s ^ (row&7) -> conflict-free b128.
// NSPLIT splits the virtual-K steps across blockIdx.z (partial fp32 outputs).
// ---------------------------------------------------------------------------
#define ISSUE(ST, RA, RB)                                                      \
  do {                                                                         \
    int s_ = (ST);                                                             \
    int sg_ = s_ / SPS;                                                        \
    int k0_ = (s_ - sg_ * SPS) * 64;                                           \
    const unsigned short* Ap_ = (sg_ < 2) ? Ah : Al;                           \
    const unsigned short* Bp_ = (sg_ == 1) ? Bl : Bh;                          \
    _Pragma("unroll") for (int i_ = 0; i_ < 4; ++i_) {                         \
      RA[i_] = *(const uint4*)(Ap_ + (size_t)(bm + crow[i_]) * lda + k0_ + csl[i_] * 8); \
      RB[i_] = *(const uint4*)(Bp_ + (size_t)(bn + crow[i_]) * ldb + k0_ + csl[i_] * 8); \
    }                                                                          \
  } while (0)

#define PHASE(IT, RWa, RWb, RLa, RLb)                                          \
  do {                                                                         \
    _Pragma("unroll") for (int i_ = 0; i_ < 4; ++i_) {                         \
      int wsl_ = csl[i_] ^ (crow[i_] & 7);                                     \
      *(uint4*)&As[crow[i_]][wsl_ * 8] = RWa[i_];                              \
      *(uint4*)&Bs[crow[i_]][wsl_ * 8] = RWb[i_];                              \
    }                                                                          \
    if ((IT) + 1 < CHUNK) { ISSUE(st0 + (IT) + 1, RLa, RLb); }                 \
    asm volatile("s_waitcnt lgkmcnt(0)\n\ts_barrier" ::: "memory");            \
    _Pragma("unroll") for (int kk = 0; kk < 2; ++kk) {                         \
      short8 af[4], bf[4];                                                     \
      _Pragma("unroll") for (int f = 0; f < 4; ++f) {                          \
        int ar = wm * 64 + f * 16 + r15;                                       \
        int as_ = (kk * 4 + ksl) ^ (ar & 7);                                   \
        af[f] = *(const short8*)&As[ar][as_ * 8];                              \
        int br = wn * 64 + f * 16 + r15;                                       \
        int bs_ = (kk * 4 + ksl) ^ (br & 7);                                   \
        bf[f] = *(const short8*)&Bs[br][bs_ * 8];                              \
      }                                                                        \
      _Pragma("unroll") for (int i_ = 0; i_ < 4; ++i_)                         \
        _Pragma("unroll") for (int j_ = 0; j_ < 4; ++j_)                       \
          acc[i_][j_] = __builtin_amdgcn_mfma_f32_16x16x32_bf16(               \
              af[i_], bf[j_], acc[i_][j_], 0, 0, 0);                           \
    }                                                                          \
    asm volatile("s_barrier" ::: "memory");                                    \
  } while (0)

template <int KSEG, int NSPLIT>
__global__ __launch_bounds__(256, 2) void gemm_bf16(
    const unsigned short* __restrict__ Ah, const unsigned short* __restrict__ Al, int lda,
    const unsigned short* __restrict__ Bh, const unsigned short* __restrict__ Bl, int ldb,
    float* __restrict__ Cout, int ldc)
{
    constexpr int SPS = KSEG / 64;
    constexpr int NST = 3 * SPS;
    constexpr int CHUNK = NST / NSPLIT;

    __shared__ __align__(16) unsigned short As[128][64];
    __shared__ __align__(16) unsigned short Bs[128][64];

    const int tid = threadIdx.x, lane = tid & 63, w = tid >> 6;
    const int wm = w >> 1, wn = w & 1;
    const int bm = blockIdx.y * 128, bn = blockIdx.x * 128;
    const int st0 = blockIdx.z * CHUNK;
    const int r15 = lane & 15, ksl = lane >> 4;

    int crow[4], csl[4];
#pragma unroll
    for (int i = 0; i < 4; ++i) { int c = tid + i * 256; crow[i] = c >> 3; csl[i] = c & 7; }

    f32x4 acc[4][4];
#pragma unroll
    for (int i = 0; i < 4; ++i)
#pragma unroll
        for (int j = 0; j < 4; ++j) acc[i][j] = (f32x4){0.f, 0.f, 0.f, 0.f};

    uint4 rA0[4], rB0[4], rA1[4], rB1[4];
    ISSUE(st0, rA0, rB0);

#pragma unroll 1
    for (int it = 0; it < CHUNK; it += 2) {
        PHASE(it,     rA0, rB0, rA1, rB1);
        PHASE(it + 1, rA1, rB1, rA0, rB0);
    }

    float* Cz = Cout + (size_t)blockIdx.z * (size_t)(gridDim.y * 128) * ldc;
#pragma unroll
    for (int i = 0; i < 4; ++i) {
        int rowb = bm + wm * 64 + i * 16 + (lane >> 4) * 4;
#pragma unroll
        for (int j = 0; j < 4; ++j) {
            int colb = bn + wn * 64 + j * 16 + r15;
#pragma unroll
            for (int r = 0; r < 4; ++r)
                Cz[(size_t)(rowb + r) * ldc + colb] = acc[i][j][r];
        }
    }
}

// ---------------------------------------------------------------------------
// Reduce NS partials + bias, write C fp32 and hi/lo bf16.
// ---------------------------------------------------------------------------
template <int NS, bool BIAS>
__global__ __launch_bounds__(256) void reduce_kernel(
    const float* __restrict__ part, size_t pstride4,
    const float* __restrict__ bias, float* __restrict__ C,
    unsigned short* __restrict__ Ch, unsigned short* __restrict__ Cl, int N)
{
    size_t idx = (size_t)blockIdx.x * 256 + threadIdx.x;
    const float4* p = (const float4*)part;
    float4 s = p[idx];
#pragma unroll
    for (int z = 1; z < NS; ++z) {
        float4 t = p[idx + (size_t)z * pstride4];
        s.x += t.x; s.y += t.y; s.z += t.z; s.w += t.w;
    }
    if (BIAS) {
        int col = (int)((idx * 4) & (size_t)(N - 1));
        s.x += bias[col]; s.y += bias[col + 1]; s.z += bias[col + 2]; s.w += bias[col + 3];
    }
    ((float4*)C)[idx] = s;
    float v[4] = {s.x, s.y, s.z, s.w};
    unsigned short h[4], l[4];
#pragma unroll
    for (int q = 0; q < 4; ++q) { h[q] = f2bf_rn(v[q]); l[q] = f2bf_rn(v[q] - bf2f(h[q])); }
    uint2 hp = make_uint2((unsigned)h[0] | ((unsigned)h[1] << 16), (unsigned)h[2] | ((unsigned)h[3] << 16));
    uint2 lp = make_uint2((unsigned)l[0] | ((unsigned)l[1] << 16), (unsigned)l[2] | ((unsigned)l[3] << 16));
    ((uint2*)Ch)[idx] = hp;
    ((uint2*)Cl)[idx] = lp;
}

// ---------------------------------------------------------------------------
// Row softmax (L=2048) -> hi/lo bf16 probs. One block per row.
// ---------------------------------------------------------------------------
__global__ __launch_bounds__(256) void softmax_ph(
    const float* __restrict__ Sc, unsigned short* __restrict__ Ph,
    unsigned short* __restrict__ Pl)
{
    __shared__ float red[8];
    const int tid = threadIdx.x;
    const size_t r = blockIdx.x;
    const float4* p4 = (const float4*)(Sc + r * 2048);
    float4 a = p4[tid * 2], b = p4[tid * 2 + 1];
    float vv[8] = {a.x, a.y, a.z, a.w, b.x, b.y, b.z, b.w};

    float mx = vv[0];
#pragma unroll
    for (int i = 1; i < 8; ++i) mx = fmaxf(mx, vv[i]);
#pragma unroll
    for (int o = 32; o; o >>= 1) mx = fmaxf(mx, __shfl_down(mx, o));
    if ((tid & 63) == 0) red[tid >> 6] = mx;
    __syncthreads();
    mx = fmaxf(fmaxf(red[0], red[1]), fmaxf(red[2], red[3]));

    float e[8], sum = 0.f;
#pragma unroll
    for (int i = 0; i < 8; ++i) { e[i] = expf(vv[i] - mx); sum += e[i]; }
#pragma unroll
    for (int o = 32; o; o >>= 1) sum += __shfl_down(sum, o);
    __syncthreads();
    if ((tid & 63) == 0) red[4 + (tid >> 6)] = sum;
    __syncthreads();
    float inv = 1.f / (red[4] + red[5] + red[6] + red[7]);

    unsigned short h[8], l[8];
#pragma unroll
    for (int i = 0; i < 8; ++i) {
        float pv = e[i] * inv;
        h[i] = f2bf_rn(pv);
        l[i] = f2bf_rn(pv - bf2f(h[i]));
    }
    uint4 hp, lp;
    hp.x = (unsigned)h[0] | ((unsigned)h[1] << 16); hp.y = (unsigned)h[2] | ((unsigned)h[3] << 16);
    hp.z = (unsigned)h[4] | ((unsigned)h[5] << 16); hp.w = (unsigned)h[6] | ((unsigned)h[7] << 16);
    lp.x = (unsigned)l[0] | ((unsigned)l[1] << 16); lp.y = (unsigned)l[2] | ((unsigned)l[3] << 16);
    lp.z = (unsigned)l[4] | ((unsigned)l[5] << 16); lp.w = (unsigned)l[6] | ((unsigned)l[7] << 16);
    ((uint4*)(Ph + r * 2048))[tid] = hp;
    ((uint4*)(Pl + r * 2048))[tid] = lp;
}

// ---------------------------------------------------------------------------
// Row L2 normalize in place (fp32), row = V + r*ld + coloff, D elems.
// ---------------------------------------------------------------------------
__global__ __launch_bounds__(256) void l2norm_kernel(float* __restrict__ V, int ld,
                                                     int coloff, int D)
{
    __shared__ float red[8];
    const int tid = threadIdx.x;
    float* p = V + (size_t)blockIdx.x * ld + coloff;
    float s = 0.f;
    for (int i = tid; i < D; i += 256) { float v = p[i]; s = fmaf(v, v, s); }
#pragma unroll
    for (int o = 32; o; o >>= 1) s += __shfl_down(s, o);
    if ((tid & 63) == 0) red[tid >> 6] = s;
    __syncthreads();
    float scale = 1.f / sqrtf(red[0] + red[1] + red[2] + red[3]);
    for (int i = tid; i < D; i += 256) p[i] *= scale;
}

// ---------------------------------------------------------------------------
// Transpose-convert: out[c + rowoff][r] (hi/lo bf16) = in[r][c] (fp32).
// grid (C/32, R/32), 256 threads.
// ---------------------------------------------------------------------------
__global__ __launch_bounds__(256) void tc_kernel(
    const float* __restrict__ in, int ldin,
    unsigned short* __restrict__ oh, unsigned short* __restrict__ ol,
    int ldo, int rowoff)
{
    __shared__ float tile[32][33];
    int bx = blockIdx.x * 32, by = blockIdx.y * 32;
    int tx = threadIdx.x & 31, ty = threadIdx.x >> 5;
#pragma unroll
    for (int i = 0; i < 32; i += 8)
        tile[ty + i][tx] = in[(size_t)(by + ty + i) * ldin + bx + tx];
    __syncthreads();
#pragma unroll
    for (int i = 0; i < 32; i += 8) {
        float v = tile[tx][ty + i];
        unsigned short h = f2bf_rn(v);
        unsigned short l = f2bf_rn(v - bf2f(h));
        size_t o = (size_t)(rowoff + bx + ty + i) * ldo + by + tx;
        oh[o] = h; ol[o] = l;
    }
}

// ---------------------------------------------------------------------------
// Elementwise fp32 -> hi/lo bf16 (no transpose). One float4 per thread.
// ---------------------------------------------------------------------------
__global__ __launch_bounds__(256) void convert_hl(
    const float* __restrict__ in, unsigned short* __restrict__ oh,
    unsigned short* __restrict__ ol)
{
    size_t idx = (size_t)blockIdx.x * 256 + threadIdx.x;
    float4 s = ((const float4*)in)[idx];
    float v[4] = {s.x, s.y, s.z, s.w};
    unsigned short h[4], l[4];
#pragma unroll
    for (int q = 0; q < 4; ++q) { h[q] = f2bf_rn(v[q]); l[q] = f2bf_rn(v[q] - bf2f(h[q])); }
    uint2 hp = make_uint2((unsigned)h[0] | ((unsigned)h[1] << 16), (unsigned)h[2] | ((unsigned)h[3] << 16));
    uint2 lp = make_uint2((unsigned)l[0] | ((unsigned)l[1] << 16), (unsigned)l[2] | ((unsigned)l[3] << 16));
    ((uint2*)oh)[idx] = hp;
    ((uint2*)ol)[idx] = lp;
}

// ---------------------------------------------------------------------------
// Bias concat: b1 = [bk1|bq1] (512), b2 = [bk2|bq2|bv2] (1024).
// ---------------------------------------------------------------------------
__global__ __launch_bounds__(256) void concat_bias(
    const float* bk1, const float* bq1, const float* bk2, const float* bq2,
    const float* bv2, float* b1, float* b2)
{
    int i = blockIdx.x * 256 + threadIdx.x;
    if (i < 512) b1[i] = (i < 256) ? bk1[i] : bq1[i - 256];
    if (i < 1024) b2[i] = (i < 256) ? bk2[i] : (i < 512 ? bq2[i - 256] : bv2[i - 512]);
}

// ---------------------------------------------------------------------------
// fp32 gemv NT: out[n] = a . Bt[n][0..K) (+bias). One wave per n, grid N/4.
// ---------------------------------------------------------------------------
template <bool HAS_BIAS>
__global__ __launch_bounds__(256) void gemv_nt(
    const float* __restrict__ a, const float* __restrict__ Bt, int ldb,
    const float* __restrict__ bias, float* __restrict__ out, int K)
{
    int w = threadIdx.x >> 6, lane = threadIdx.x & 63;
    int n = blockIdx.x * 4 + w;
    const float* row = Bt + (size_t)n * ldb;
    float s = 0.f;
    for (int k = lane; k < K; k += 64) s = fmaf(a[k], row[k], s);
#pragma unroll
    for (int o = 32; o; o >>= 1) s += __shfl_down(s, o);
    if (lane == 0) out[n] = HAS_BIAS ? s + bias[n] : s;
}

// gemv over hi/lo bf16 rows: out[d] = sum_k p[k]*(h+l). One wave per d.
__global__ __launch_bounds__(256) void gemv_hl(
    const float* __restrict__ p, const unsigned short* __restrict__ Vh,
    const unsigned short* __restrict__ Vl, int ld, float* __restrict__ out, int K)
{
    int w = threadIdx.x >> 6, lane = threadIdx.x & 63;
    int d = blockIdx.x * 4 + w;
    const unsigned short* rh = Vh + (size_t)d * ld;
    const unsigned short* rl = Vl + (size_t)d * ld;
    float s = 0.f;
    for (int k = lane; k < K; k += 64) s = fmaf(p[k], bf2f(rh[k]) + bf2f(rl[k]), s);
#pragma unroll
    for (int o = 32; o; o >>= 1) s += __shfl_down(s, o);
    if (lane == 0) out[d] = s;
}

// ---------------------------------------------------------------------------
// Row softmax fp32 in place (block-3 single row).
// ---------------------------------------------------------------------------
__global__ __launch_bounds__(256) void softmax_f32(float* __restrict__ S, int L)
{
    __shared__ float row[2048];
    __shared__ float red[8];
    const int tid = threadIdx.x;
    float* p = S + (size_t)blockIdx.x * L;
    float mx = -1e30f;
    for (int i = tid; i < L; i += 256) { float v = p[i]; row[i] = v; mx = fmaxf(mx, v); }
#pragma unroll
    for (int o = 32; o; o >>= 1) mx = fmaxf(mx, __shfl_down(mx, o));
    if ((tid & 63) == 0) red[tid >> 6] = mx;
    __syncthreads();
    mx = fmaxf(fmaxf(red[0], red[1]), fmaxf(red[2], red[3]));
    float sum = 0.f;
    for (int i = tid; i < L; i += 256) { float e = expf(row[i] - mx); row[i] = e; sum += e; }
#pragma unroll
    for (int o = 32; o; o >>= 1) sum += __shfl_down(sum, o);
    __syncthreads();
    if ((tid & 63) == 0) red[4 + (tid >> 6)] = sum;
    __syncthreads();
    float inv = 1.f / (red[4] + red[5] + red[6] + red[7]);
    for (int i = tid; i < L; i += 256) p[i] = row[i] * inv;
}

// ---------------------------------------------------------------------------
// Orchestration (batch 0 only; block 3 needs only the last query row).
// ---------------------------------------------------------------------------
extern "C" void kernel_launch(void* const* d_in, const int* in_sizes, int n_in,
                              void* d_out, int out_size, void* d_ws, size_t ws_size,
                              hipStream_t stream)
{
    const float* x   = (const float*)d_in[0];
    const float* Wk1 = (const float*)d_in[1];
    const float* bk1 = (const float*)d_in[2];
    const float* Wq1 = (const float*)d_in[3];
    const float* bq1 = (const float*)d_in[4];
    const float* Wk2 = (const float*)d_in[5];
    const float* bk2 = (const float*)d_in[6];
    const float* Wq2 = (const float*)d_in[7];
    const float* bq2 = (const float*)d_in[8];
    const float* Wv2 = (const float*)d_in[9];
    const float* bv2 = (const float*)d_in[10];
    float* out = (float*)d_out;

    const int S = 2048, D = 512;
    typedef unsigned short us;

    char* p = (char*)d_ws;
    float* C    = (float*)p;            p += (size_t)S * 1024 * 4;   // proj fp32 out
    float* SCP  = (float*)p;            p += (size_t)S * S * 4;      // scores / GEMM partials
    float* H    = (float*)p;            p += (size_t)S * D * 4;
    us* Ph  = (us*)p; p += (size_t)S * S * 2;
    us* Pl  = (us*)p; p += (size_t)S * S * 2;
    us* Chh = (us*)p; p += (size_t)S * 1024 * 2;
    us* Cll = (us*)p; p += (size_t)S * 1024 * 2;
    us* Hh  = (us*)p; p += (size_t)S * D * 2;
    us* Hl  = (us*)p; p += (size_t)S * D * 2;
    us* xh  = (us*)p; p += (size_t)S * D * 2;
    us* xl  = (us*)p; p += (size_t)S * D * 2;
    us* VTh = (us*)p; p += (size_t)D * S * 2;
    us* VTl = (us*)p; p += (size_t)D * S * 2;
    us* WT1h = (us*)p; p += (size_t)512 * 512 * 2;
    us* WT1l = (us*)p; p += (size_t)512 * 512 * 2;
    us* WT2h = (us*)p; p += (size_t)1024 * 512 * 2;
    us* WT2l = (us*)p; p += (size_t)1024 * 512 * 2;
    float* b1 = (float*)p; p += 512 * 4;
    float* b2 = (float*)p; p += 1024 * 4;

    dim3 blk(256);
    const size_t PSTR  = (size_t)S * 512 / 4;    // 512-wide partial stride (float4)
    const size_t PSTR2 = (size_t)S * 1024 / 4;   // 1024-wide

    // ---- setup: converts, transposes, bias concat ----
    convert_hl<<<dim3(S * D / 1024), blk, 0, stream>>>(x, xh, xl);
    tc_kernel<<<dim3(16, 64), blk, 0, stream>>>(x, 512, VTh, VTl, S, 0);     // x^T
    tc_kernel<<<dim3(8, 16), blk, 0, stream>>>(Wk1, 256, WT1h, WT1l, 512, 0);
    tc_kernel<<<dim3(8, 16), blk, 0, stream>>>(Wq1, 256, WT1h, WT1l, 512, 256);
    tc_kernel<<<dim3(8, 16), blk, 0, stream>>>(Wk2, 256, WT2h, WT2l, 512, 0);
    tc_kernel<<<dim3(8, 16), blk, 0, stream>>>(Wq2, 256, WT2h, WT2l, 512, 256);
    tc_kernel<<<dim3(16, 16), blk, 0, stream>>>(Wv2, 512, WT2h, WT2l, 512, 512);
    concat_bias<<<dim3(4), blk, 0, stream>>>(bk1, bq1, bk2, bq2, bv2, b1, b2);

    // ---- block 1: proj (K|Q fused), scores, softmax, AV ----
    gemm_bf16<512, 3><<<dim3(4, 16, 3), blk, 0, stream>>>(xh, xl, 512, WT1h, WT1l, 512, SCP, 512);
    reduce_kernel<3, true><<<dim3(S * 512 / 1024), blk, 0, stream>>>(SCP, PSTR, b1, C, Chh, Cll, 512);
    gemm_bf16<256, 1><<<dim3(16, 16, 1), blk, 0, stream>>>(Chh + 256, Cll + 256, 512, Chh, Cll, 512, SCP, 2048);
    softmax_ph<<<dim3(S), blk, 0, stream>>>(SCP, Ph, Pl);
    gemm_bf16<2048, 4><<<dim3(4, 16, 4), blk, 0, stream>>>(Ph, Pl, 2048, VTh, VTl, 2048, SCP, 512);
    reduce_kernel<4, false><<<dim3(S * 512 / 1024), blk, 0, stream>>>(SCP, PSTR, nullptr, H, Hh, Hl, 512);

    // ---- block 2: proj (K|Q|V fused), l2norm, V^T, scores, softmax, AV ----
    gemm_bf16<512, 2><<<dim3(8, 16, 2), blk, 0, stream>>>(Hh, Hl, 512, WT2h, WT2l, 512, SCP, 1024);
    reduce_kernel<2, true><<<dim3(S * 1024 / 1024), blk, 0, stream>>>(SCP, PSTR2, b2, C, Chh, Cll, 1024);
    l2norm_kernel<<<dim3(S), blk, 0, stream>>>(C, 1024, 512, 512);
    tc_kernel<<<dim3(16, 64), blk, 0, stream>>>(C + 512, 1024, VTh, VTl, S, 0);
    gemm_bf16<256, 1><<<dim3(16, 16, 1), blk, 0, stream>>>(Chh + 256, Cll + 256, 1024, Chh, Cll, 1024, SCP, 2048);
    softmax_ph<<<dim3(S), blk, 0, stream>>>(SCP, Ph, Pl);
    gemm_bf16<2048, 4><<<dim3(4, 16, 4), blk, 0, stream>>>(Ph, Pl, 2048, VTh, VTl, 2048, SCP, 512);
    reduce_kernel<4, false><<<dim3(S * 512 / 1024), blk, 0, stream>>>(SCP, PSTR, nullptr, H, Hh, Hl, 512);

    // ---- block 3: proj, l2norm, V^T, then 1-row attention ----
    gemm_bf16<512, 2><<<dim3(8, 16, 2), blk, 0, stream>>>(Hh, Hl, 512, WT2h, WT2l, 512, SCP, 1024);
    reduce_kernel<2, true><<<dim3(S * 1024 / 1024), blk, 0, stream>>>(SCP, PSTR2, b2, C, Chh, Cll, 1024);
    l2norm_kernel<<<dim3(S), blk, 0, stream>>>(C, 1024, 512, 512);
    tc_kernel<<<dim3(16, 64), blk, 0, stream>>>(C + 512, 1024, VTh, VTl, S, 0);
    gemv_nt<false><<<dim3(S / 4), blk, 0, stream>>>(C + (size_t)(S - 1) * 1024 + 256, C, 1024, nullptr, SCP, 256);
    softmax_f32<<<dim3(1), blk, 0, stream>>>(SCP, S);
    gemv_hl<<<dim3(D / 4), blk, 0, stream>>>(SCP, VTh, VTl, S, out, S);
}